// Round 10
// baseline (300.734 us; speedup 1.0000x reference)
//
#include <hip/hip_runtime.h>
#include <hip/hip_bf16.h>

// ---- problem constants ----
#define M_IMG 1008
#define N_PCD 1024
#define CDIM  256
#define NI_F  76800
#define NP_F  30000
#define KI    64
#define KP    64
#define NUM_CORR 256
#define NPAIR (NUM_CORR * KI)       // 16384
#define CAND_CAP 4096
#define KEY_MOD 30001u

#define NEG_INF (-__builtin_inff())
typedef unsigned long long u64;

// bool inputs may arrive as uint8 (numpy bool) or int32 (harness "integer")
// layouts. Detected at runtime; *flag != 0 means uint8.
__device__ __forceinline__ bool mask_val(const void* p, int i, int is_u8) {
    return is_u8 ? (((const unsigned char*)p)[i] != 0)
                 : (((const int*)p)[i] != 0);
}

// Kernel 0: detect bool layout from pcd_knn_msk (65536 elements, ~90% true).
__global__ void detect_bool_kernel(const unsigned int* __restrict__ p,
                                   int* __restrict__ flag) {
    __shared__ int s_cnt;
    if (threadIdx.x == 0) s_cnt = 0;
    __syncthreads();
    unsigned int x = p[blockIdx.x * 256 + threadIdx.x];
    if (x & 0xFFFFFF00u) atomicAdd(&s_cnt, 1);
    __syncthreads();
    if (threadIdx.x == 0 && s_cnt != 0) atomicAdd(flag, 1);
}

// ---- top-3 helpers (values only, multiplicity preserved) ----
__device__ __forceinline__ void top3_insert(float v, float& t0, float& t1, float& t2) {
    if (v > t0) { t2 = t1; t1 = t0; t0 = v; }
    else if (v > t1) { t2 = t1; t1 = v; }
    else if (v > t2) { t2 = v; }
}

__device__ __forceinline__ void top3_merge(float a0, float a1, float a2,
                                           float b0, float b1, float b2,
                                           float& x0, float& x1, float& x2) {
    if (a0 >= b0) {
        x0 = a0;
        if (a1 >= b0) { x1 = a1; x2 = (a2 >= b0) ? a2 : b0; }
        else          { x1 = b0; x2 = (a1 >= b1) ? a1 : b1; }
    } else {
        x0 = b0;
        if (b1 >= a0) { x1 = b1; x2 = (b2 >= a0) ? b2 : a0; }
        else          { x1 = a0; x2 = (b1 >= a1) ? b1 : a1; }
    }
}

// =====================================================================
// Kernel A: coarse sim = img_c @ pcd_c^T (masked), FUSED with per-tile
// row/col top-3 partials. grid(16,32)x256, 32x64 tile per block.
// Pipelined K-loop (register-prefetch next chunk during compute).
// rowp[3][16][1024] (chunk=blockIdx.x), colp[3][32][1024] (chunk=blockIdx.y).
// =====================================================================
__global__ void coarse_sim_kernel(const float* __restrict__ A,   // [1008,256]
                                  const float* __restrict__ B,   // [1024,256]
                                  const void* __restrict__ maskA,
                                  const void* __restrict__ maskB,
                                  const int* __restrict__ flag,
                                  float* __restrict__ sim,       // [1008,1024]
                                  float* __restrict__ rowp,
                                  float* __restrict__ colp) {
    __shared__ __align__(16) float s_a[32][36];
    __shared__ __align__(16) float s_b[32][68];
    __shared__ float sr[32][16][3];
    __shared__ float sc[64][16][3];
    const int is_u8 = (*flag != 0);
    const int m0 = blockIdx.y * 32, n0 = blockIdx.x * 64;
    const int tid = threadIdx.x;
    const int tx = tid & 15, ty = tid >> 4;      // ty: 2 rows each
    const int c_lane = tid & 31;
    const int r_base = tid >> 5;                 // 0..7

    const float* pa[4];
    const float* pb[8];
#pragma unroll
    for (int k = 0; k < 4; k++) {
        int m = m0 + r_base + 8 * k;
        pa[k] = A + (size_t)(m < M_IMG ? m : 0) * CDIM + c_lane;
    }
#pragma unroll
    for (int k = 0; k < 8; k++)
        pb[k] = B + (size_t)(n0 + r_base + 8 * k) * CDIM + c_lane;

    float ra[4], rb[8];
#pragma unroll
    for (int k = 0; k < 4; k++) ra[k] = pa[k][0];
#pragma unroll
    for (int k = 0; k < 8; k++) rb[k] = pb[k][0];
#pragma unroll
    for (int k = 0; k < 4; k++) s_a[c_lane][r_base + 8 * k] = ra[k];
#pragma unroll
    for (int k = 0; k < 8; k++) s_b[c_lane][r_base + 8 * k] = rb[k];
    __syncthreads();

    float acc[2][4];
#pragma unroll
    for (int r = 0; r < 2; r++)
#pragma unroll
        for (int j = 0; j < 4; j++) acc[r][j] = 0.f;

    for (int cit = 0; cit < 8; cit++) {
        if (cit < 7) {
            const int cc = (cit + 1) * 32;
#pragma unroll
            for (int k = 0; k < 4; k++) ra[k] = pa[k][cc];
#pragma unroll
            for (int k = 0; k < 8; k++) rb[k] = pb[k][cc];
        }
#pragma unroll 8
        for (int c = 0; c < 32; c++) {
            float2 av = *(const float2*)&s_a[c][ty * 2];
            float4 bv = *(const float4*)&s_b[c][tx * 4];
            float ar[2] = {av.x, av.y};
            float br[4] = {bv.x, bv.y, bv.z, bv.w};
#pragma unroll
            for (int r = 0; r < 2; r++)
#pragma unroll
                for (int j = 0; j < 4; j++) acc[r][j] += ar[r] * br[j];
        }
        __syncthreads();
        if (cit < 7) {
#pragma unroll
            for (int k = 0; k < 4; k++) s_a[c_lane][r_base + 8 * k] = ra[k];
#pragma unroll
            for (int k = 0; k < 8; k++) s_b[c_lane][r_base + 8 * k] = rb[k];
            __syncthreads();
        }
    }

    // epilogue: masked values + sim write + row/col top-3 partials
    float vm[2][4];
#pragma unroll
    for (int r = 0; r < 2; r++) {
        int m = m0 + ty * 2 + r;
        bool ma = (m < M_IMG) && mask_val(maskA, m, is_u8);
#pragma unroll
        for (int j = 0; j < 4; j++) {
            int n = n0 + tx * 4 + j;
            bool ok = ma && mask_val(maskB, n, is_u8);
            float v = ok ? acc[r][j] : NEG_INF;
            vm[r][j] = v;
            if (m < M_IMG) sim[m * N_PCD + n] = v;
        }
    }
#pragma unroll
    for (int r = 0; r < 2; r++) {
        float t0 = NEG_INF, t1 = NEG_INF, t2 = NEG_INF;
#pragma unroll
        for (int j = 0; j < 4; j++) top3_insert(vm[r][j], t0, t1, t2);
        sr[ty * 2 + r][tx][0] = t0; sr[ty * 2 + r][tx][1] = t1; sr[ty * 2 + r][tx][2] = t2;
    }
#pragma unroll
    for (int j = 0; j < 4; j++) {
        float t0 = NEG_INF, t1 = NEG_INF, t2 = NEG_INF;
        top3_insert(vm[0][j], t0, t1, t2);
        top3_insert(vm[1][j], t0, t1, t2);
        sc[tx * 4 + j][ty][0] = t0; sc[tx * 4 + j][ty][1] = t1; sc[tx * 4 + j][ty][2] = t2;
    }
    __syncthreads();
    if (tid < 32) {
        float t0 = sr[tid][0][0], t1 = sr[tid][0][1], t2 = sr[tid][0][2];
#pragma unroll
        for (int k = 1; k < 16; k++) {
            float x0, x1, x2;
            top3_merge(t0, t1, t2, sr[tid][k][0], sr[tid][k][1], sr[tid][k][2], x0, x1, x2);
            t0 = x0; t1 = x1; t2 = x2;
        }
        int m = m0 + tid;
        if (m < M_IMG) {
            const int base = blockIdx.x * 1024 + m;
            rowp[base] = t0;
            rowp[16 * 1024 + base] = t1;
            rowp[2 * 16 * 1024 + base] = t2;
        }
    } else if (tid >= 64 && tid < 128) {
        int col = tid - 64;
        float t0 = sc[col][0][0], t1 = sc[col][0][1], t2 = sc[col][0][2];
#pragma unroll
        for (int k = 1; k < 16; k++) {
            float x0, x1, x2;
            top3_merge(t0, t1, t2, sc[col][k][0], sc[col][k][1], sc[col][k][2], x0, x1, x2);
            t0 = x0; t1 = x1; t2 = x2;
        }
        const int base = blockIdx.y * 1024 + n0 + col;
        colp[base] = t0;
        colp[32 * 1024 + base] = t1;
        colp[2 * 32 * 1024 + base] = t2;
    }
}

// Kernel B: merge partials -> row_kth / col_kth. grid(8)x256.
// Blocks 0-3: rows (merge 16 chunks); blocks 4-7: cols (merge 32 chunks).
__global__ void kth_merge_kernel(const float* __restrict__ rowp,
                                 const float* __restrict__ colp,
                                 float* __restrict__ row_kth,
                                 float* __restrict__ col_kth) {
    const int b = blockIdx.x, t = threadIdx.x;
    if (b < 4) {
        int m = b * 256 + t;
        if (m >= M_IMG) return;
        float t0 = rowp[m], t1 = rowp[16 * 1024 + m], t2 = rowp[2 * 16 * 1024 + m];
#pragma unroll
        for (int ch = 1; ch < 16; ch++) {
            int base = ch * 1024 + m;
            float x0, x1, x2;
            top3_merge(t0, t1, t2, rowp[base], rowp[16 * 1024 + base],
                       rowp[2 * 16 * 1024 + base], x0, x1, x2);
            t0 = x0; t1 = x1; t2 = x2;
        }
        row_kth[m] = t2;
    } else {
        int n = (b - 4) * 256 + t;
        float t0 = colp[n], t1 = colp[32 * 1024 + n], t2 = colp[2 * 32 * 1024 + n];
#pragma unroll
        for (int ch = 1; ch < 32; ch++) {
            int base = ch * 1024 + n;
            float x0, x1, x2;
            top3_merge(t0, t1, t2, colp[base], colp[32 * 1024 + base],
                       colp[2 * 32 * 1024 + base], x0, x1, x2);
            t0 = x0; t1 = x1; t2 = x2;
        }
        col_kth[n] = t2;
    }
}

// Kernel D: compact mutual candidates. grid(4032)x256
__global__ void compact_kernel(const float* __restrict__ sim,
                               const float* __restrict__ row_kth,
                               const float* __restrict__ col_kth,
                               u64* __restrict__ cand,
                               int* __restrict__ count) {
    int g = blockIdx.x * 256 + threadIdx.x;
    if (g >= M_IMG * N_PCD) return;
    int m = g >> 10, n = g & 1023;
    float v = sim[g];
    if (v > 0.f && v >= row_kth[m] && v >= col_kth[n]) {
        int pos = atomicAdd(count, 1);
        if (pos < CAND_CAP) {
            unsigned int u = __float_as_uint(v);
            unsigned int mono = (u & 0x80000000u) ? ~u : (u | 0x80000000u); // ascending map
            cand[pos] = ((u64)(~mono) << 32) | (unsigned int)g; // asc sort => val desc, idx asc
        }
    }
}

// =====================================================================
// Kernel E: self-contained candidate rank + top-256 select. grid(16)x256.
// Keys unique (distinct flat idx) -> rank = #{cand < mine} is an exact
// permutation; ascending packed = (value desc, idx asc) = lax.top_k order.
// Output order irrelevant (final out[] depends only on the selected SET).
// =====================================================================
__global__ void cand_rank_select_kernel(const u64* __restrict__ cand,
                                        const int* __restrict__ count,
                                        int* __restrict__ sel_idx,
                                        int* __restrict__ selK) {
    __shared__ u64 s[256];
    const int tid = threadIdx.x, bi = blockIdx.x;
    int K = *count; if (K > CAND_CAP) K = CAND_CAP;
    if (bi == 0 && tid == 0) *selK = (K < NUM_CORR) ? K : NUM_CORR;
    if (bi * 256 >= K) return;
    const int i = bi * 256 + tid;
    const u64 my = (i < K) ? cand[i] : 0xFFFFFFFFFFFFFFFFull;
    unsigned int less = 0;
    for (int c0 = 0; c0 < K; c0 += 256) {
        int j = c0 + tid;
        s[tid] = (j < K) ? cand[j] : 0xFFFFFFFFFFFFFFFFull;
        __syncthreads();
#pragma unroll 8
        for (int t = 0; t < 256; t++) less += (s[t] < my);
        __syncthreads();
    }
    if (i < K && less < NUM_CORR) sel_idx[less] = (int)(my & 0xFFFFFFFFull);
}

// =====================================================================
// Kernel F: fine matching, one block per correspondence. grid(256)x512.
// Pipelined GEMM; selected pairs appended to vlist as (key<<14)|idx
// packed u46 (key < 2^32, idx < 2^14). Sentinels/dups need no entry:
// out[] is pre-zeroed and their positions hold 0.
// =====================================================================
__global__ void fine_kernel(const float* __restrict__ img_f,   // [76800,256]
                            const float* __restrict__ pcd_f,   // [30000,256]
                            const int* __restrict__ img_knn,   // [1008,64]
                            const int* __restrict__ pcd_knn,   // [1024,64]
                            const void* __restrict__ pcd_msk,  // [1024,64] bool
                            const int* __restrict__ flag,
                            const int* __restrict__ sel_idx,
                            const int* __restrict__ selK_ptr,
                            u64* __restrict__ vlist,
                            int* __restrict__ nvcnt) {
    const int ci = blockIdx.x, tid = threadIdx.x;
    const int selK = *selK_ptr;
    if (ci >= selK) return;
    __shared__ int s_ik[KI], s_pk[KP];
    __shared__ unsigned char s_mk[KP];
    __shared__ __align__(16) float s_a[32][68];
    __shared__ __align__(16) float s_b[32][68];
    __shared__ float s_sim[64][65];
    __shared__ int s_rb[64], s_cb[64];
    __shared__ float s_rv[64];

    int flat = sel_idx[ci];
    int gi = flat >> 10, pi = flat & 1023;
    if (tid < 64) {
        const int is_u8 = (*flag != 0);
        s_ik[tid] = img_knn[gi * KI + tid];
        s_pk[tid] = pcd_knn[pi * KP + tid];
        s_mk[tid] = mask_val(pcd_msk, pi * KP + tid, is_u8) ? 1 : 0;
    }
    __syncthreads();

    const int tx = tid & 15, tyy = tid >> 4;     // tyy 0..31 -> 2 rows each
    const int c_lane = tid & 31;
    const int r_base = tid >> 5;                 // 0..15 -> 4 rows each

    const float* pa[4];
    const float* pb[4];
#pragma unroll
    for (int k = 0; k < 4; k++) {
        pa[k] = img_f + (size_t)s_ik[r_base + 16 * k] * CDIM + c_lane;
        pb[k] = pcd_f + (size_t)s_pk[r_base + 16 * k] * CDIM + c_lane;
    }

    float ra[4], rb[4];
#pragma unroll
    for (int k = 0; k < 4; k++) { ra[k] = pa[k][0]; rb[k] = pb[k][0]; }
#pragma unroll
    for (int k = 0; k < 4; k++) {
        s_a[c_lane][r_base + 16 * k] = ra[k];
        s_b[c_lane][r_base + 16 * k] = rb[k];
    }
    __syncthreads();

    float acc[2][4];
#pragma unroll
    for (int r = 0; r < 2; r++)
#pragma unroll
        for (int j = 0; j < 4; j++) acc[r][j] = 0.f;

    for (int cit = 0; cit < 8; cit++) {
        if (cit < 7) {
            const int cc = (cit + 1) * 32;
#pragma unroll
            for (int k = 0; k < 4; k++) { ra[k] = pa[k][cc]; rb[k] = pb[k][cc]; }
        }
#pragma unroll 8
        for (int c = 0; c < 32; c++) {
            float2 av = *(const float2*)&s_a[c][tyy * 2];
            float4 bv = *(const float4*)&s_b[c][tx * 4];
            float ar[2] = {av.x, av.y};
            float br[4] = {bv.x, bv.y, bv.z, bv.w};
#pragma unroll
            for (int r = 0; r < 2; r++)
#pragma unroll
                for (int j = 0; j < 4; j++) acc[r][j] += ar[r] * br[j];
        }
        __syncthreads();
        if (cit < 7) {
#pragma unroll
            for (int k = 0; k < 4; k++) {
                s_a[c_lane][r_base + 16 * k] = ra[k];
                s_b[c_lane][r_base + 16 * k] = rb[k];
            }
            __syncthreads();
        }
    }
#pragma unroll
    for (int r = 0; r < 2; r++) {
        int row = tyy * 2 + r;
#pragma unroll
        for (int j = 0; j < 4; j++) {
            int kp = tx * 4 + j;
            s_sim[row][kp] = (s_mk[kp] != 0) ? acc[r][j] : NEG_INF;
        }
    }
    __syncthreads();

    if (tid < 64) {              // row argmax over kp (first-max semantics)
        float best = NEG_INF; int bi = 0;
        for (int kp = 0; kp < 64; kp++) {
            float v = s_sim[tid][kp];
            if (v > best) { best = v; bi = kp; }
        }
        s_rb[tid] = bi; s_rv[tid] = best;
    } else if (tid < 128) {      // col argmax over ki
        int kp = tid - 64;
        float best = NEG_INF; int bi = 0;
        for (int k2 = 0; k2 < 64; k2++) {
            float v = s_sim[k2][kp];
            if (v > best) { best = v; bi = k2; }
        }
        s_cb[kp] = bi;
    }
    __syncthreads();

    if (tid < 64) {
        int rb2 = s_rb[tid];
        float rv = s_rv[tid];
        bool sel = (s_cb[rb2] == tid) && (rv > 0.f);  // mutual top-1 + finite + >FINE_THR
        if (sel) {
            unsigned int key = (unsigned int)s_ik[tid] * KEY_MOD + (unsigned int)s_pk[rb2];
            int pos = atomicAdd(nvcnt, 1);
            vlist[pos] = ((u64)key << 14) | (unsigned int)(ci * KI + tid);
        }
    }
}

// =====================================================================
// Kernel G1: valid-pair rank via packed counting. grid(64,64)x256 with
// data-dependent early-out. rank = #{packed < mine} (lexicographic
// (key,idx) = stable-sort position among valid entries); dup counts
// same-key-smaller-idx for first-occurrence detection.
// cntv[i] += (less<<16) | dup  (both < 2^14).
// =====================================================================
__global__ void pair_rank_kernel(const u64* __restrict__ vlist,
                                 const int* __restrict__ nvp,
                                 unsigned int* __restrict__ cntv) {
    const int nv = *nvp;
    const int bi = blockIdx.x, bj = blockIdx.y, tid = threadIdx.x;
    if (bi * 256 >= nv || bj * 256 >= nv) return;
    __shared__ u64 s[256];
    int j = bj * 256 + tid;
    s[tid] = (j < nv) ? vlist[j] : 0xFFFFFFFFFFFFFFFFull;
    __syncthreads();
    const int i = bi * 256 + tid;
    if (i >= nv) return;
    const u64 p = vlist[i];
    const u64 mykey = p >> 14;
    unsigned int less = 0, dup = 0;
#pragma unroll 8
    for (int t = 0; t < 256; t++) {
        u64 q = s[t];
        bool lt = q < p;
        less += lt;
        dup += lt && ((q >> 14) == mykey);
    }
    atomicAdd(&cntv[i], (less << 16) | dup);
}

// Kernel G2: first-occurrence valid pairs -> gather dot -> out[rank].
// Everything else (dups, sentinels) stays at the pre-zeroed 0. grid(64)x256.
__global__ void pair_out_kernel(const u64* __restrict__ vlist,
                                const int* __restrict__ nvp,
                                const unsigned int* __restrict__ cntv,
                                const float* __restrict__ img_f,
                                const float* __restrict__ pcd_f,
                                float* __restrict__ out) {
    const int nv = *nvp;
    const int i = blockIdx.x * 256 + threadIdx.x;
    if (i >= nv) return;
    const unsigned int v = cntv[i];
    if (v & 0xFFFFu) return;                     // duplicate -> stays 0
    const u64 p = vlist[i];
    const unsigned int key = (unsigned int)(p >> 14);
    const unsigned int rank = v >> 16;
    unsigned int ic = key / KEY_MOD;
    unsigned int pc = key - ic * KEY_MOD;
    const float4* a = (const float4*)(img_f + (size_t)ic * CDIM);
    const float4* b = (const float4*)(pcd_f + (size_t)pc * CDIM);
    float s = 0.f;
#pragma unroll 8
    for (int c = 0; c < CDIM / 4; c++) {
        float4 x = a[c], y = b[c];
        s += x.x * y.x + x.y * y.y + x.z * y.z + x.w * y.w;
    }
    out[rank] = s;
}

// =====================================================================
extern "C" void kernel_launch(void* const* d_in, const int* in_sizes, int n_in,
                              void* d_out, int out_size, void* d_ws, size_t ws_size,
                              hipStream_t stream) {
    const float* img_c = (const float*)d_in[0];
    const float* pcd_c = (const float*)d_in[1];
    const float* img_f = (const float*)d_in[2];
    const float* pcd_f = (const float*)d_in[3];
    const void* img_mask = d_in[4];
    const void* pcd_mask = d_in[5];
    const int* img_knn = (const int*)d_in[6];
    const int* pcd_knn = (const int*)d_in[7];
    const void* pcd_knn_msk = d_in[8];
    float* out = (float*)d_out;

    // ---- workspace layout ----
    char* w = (char*)d_ws;
    size_t off = 0;
    float* sim = (float*)(w + off);            off += (size_t)M_IMG * N_PCD * 4;
    float* row_kth = (float*)(w + off);        off += 1024 * 4;
    float* col_kth = (float*)(w + off);        off += 1024 * 4;
    // zero region: count, selK, boolflag, nvcnt, cntv  (one memset)
    int* count = (int*)(w + off);              off += 4;
    int* selK = (int*)(w + off);               off += 4;
    int* boolflag = (int*)(w + off);           off += 4;
    int* nvcnt = (int*)(w + off);              off += 4;
    unsigned int* cntv = (unsigned int*)(w + off); off += NPAIR * 4;
    off = (off + 7) & ~(size_t)7;
    u64* cand = (u64*)(w + off);               off += CAND_CAP * 8;
    int* sel_idx = (int*)(w + off);            off += NUM_CORR * 4;
    u64* vlist = (u64*)(w + off);              off += NPAIR * 8;
    float* rowp = (float*)(w + off);           off += 3 * 16 * 1024 * 4;
    float* colp = (float*)(w + off);           off += 3 * 32 * 1024 * 4;

    hipMemsetAsync(count, 0, 16 + NPAIR * 4, stream);   // counters + cntv
    hipMemsetAsync(out, 0, (size_t)out_size * 4, stream); // dups/sentinels -> 0

    detect_bool_kernel<<<16, 256, 0, stream>>>((const unsigned int*)pcd_knn_msk, boolflag);
    coarse_sim_kernel<<<dim3(16, 32), 256, 0, stream>>>(img_c, pcd_c, img_mask, pcd_mask,
                                                        boolflag, sim, rowp, colp);
    kth_merge_kernel<<<8, 256, 0, stream>>>(rowp, colp, row_kth, col_kth);
    compact_kernel<<<(M_IMG * N_PCD) / 256, 256, 0, stream>>>(sim, row_kth, col_kth, cand, count);
    cand_rank_select_kernel<<<16, 256, 0, stream>>>(cand, count, sel_idx, selK);
    fine_kernel<<<NUM_CORR, 512, 0, stream>>>(img_f, pcd_f, img_knn, pcd_knn, pcd_knn_msk,
                                              boolflag, sel_idx, selK, vlist, nvcnt);
    pair_rank_kernel<<<dim3(64, 64), 256, 0, stream>>>(vlist, nvcnt, cntv);
    pair_out_kernel<<<64, 256, 0, stream>>>(vlist, nvcnt, cntv, img_f, pcd_f, out);
}